// Round 1
// baseline (2596.582 us; speedup 1.0000x reference)
//
#include <hip/hip_runtime.h>
#include <hip/hip_bf16.h>

#define NN 10000
#define NE 100000

typedef __bf16 bf16x8 __attribute__((ext_vector_type(8)));
typedef __bf16 bf16x4 __attribute__((ext_vector_type(4)));
typedef float  f32x4  __attribute__((ext_vector_type(4)));

__device__ __forceinline__ f32x4 relu4(f32x4 a) {
    a.x = fmaxf(a.x, 0.f); a.y = fmaxf(a.y, 0.f);
    a.z = fmaxf(a.z, 0.f); a.w = fmaxf(a.w, 0.f);
    return a;
}

// ---------------- one-time kernels ----------------

__global__ void k_deg(const int* __restrict__ eidx, int* __restrict__ deg) {
    int e = blockIdx.x * blockDim.x + threadIdx.x;
    if (e < NE) atomicAdd(&deg[eidx[e]], 1);
}

__global__ void k_init(const float* __restrict__ x, const float* __restrict__ fc1w,
                       const float* __restrict__ fc1b, const float* __restrict__ cinit,
                       const int* __restrict__ deg,
                       float* __restrict__ h, float* __restrict__ coord,
                       float* __restrict__ deg_inv) {
    int n = blockIdx.x * blockDim.x + threadIdx.x;
    if (n >= NN) return;
    float x0 = x[n*3+0], x1 = x[n*3+1], x2 = x[n*3+2];
    #pragma unroll
    for (int j = 0; j < 32; j += 4) {
        f32x4 a = *(const f32x4*)(fc1b + j);
        a += x0 * (*(const f32x4*)(fc1w + 0*32 + j));
        a += x1 * (*(const f32x4*)(fc1w + 1*32 + j));
        a += x2 * (*(const f32x4*)(fc1w + 2*32 + j));
        *(f32x4*)(h + n*32 + j) = a;   // NOTE: no relu on fc1 (matches reference)
    }
    coord[n*3+0] = cinit[n*3+0];
    coord[n*3+1] = cinit[n*3+1];
    coord[n*3+2] = cinit[n*3+2];
    int d = deg[n];
    deg_inv[n] = 1.0f / (float)(d > 1 ? d : 1);
}

// Swizzle ker_w3 [128,1024] fp32 -> bf16 in MFMA-B fragment order.
// frag id = ((i*2+jt)*4+ks), lane L supplies B[k=(L>>4)*8+jj][n=L&15]
// dst index == tid by construction.
__global__ void k_w3sw(const float* __restrict__ w3, __bf16* __restrict__ w3sw) {
    int t = blockIdx.x * blockDim.x + threadIdx.x;   // 0 .. 131071
    int jj = t & 7;
    int L  = (t >> 3) & 63;
    int ks = (t >> 9) & 3;
    int jt = (t >> 11) & 1;
    int i  = t >> 12;
    int c    = ks*32 + (L >> 4)*8 + jj;              // K index 0..127
    int colv = i*32 + jt*16 + (L & 15);              // output col 0..1023
    w3sw[t] = (__bf16)w3[c*1024 + colv];
}

// ---------------- per-layer kernels ----------------

// Per-edge: coord_diff, radial, kernel MLP 7->64->128 (relu), store k as bf16 [E,128].
__global__ void k_edge(const float* __restrict__ coord, const int* __restrict__ eidx,
                       const float* __restrict__ eattr,
                       const float* __restrict__ w1, const float* __restrict__ b1,
                       const float* __restrict__ w2, const float* __restrict__ b2,
                       float* __restrict__ cd4, __bf16* __restrict__ kbf) {
    int e = blockIdx.x * blockDim.x + threadIdx.x;
    if (e >= NE) return;
    int r = eidx[e], c = eidx[NE + e];
    float dx = coord[r*3+0] - coord[c*3+0];
    float dy = coord[r*3+1] - coord[c*3+1];
    float dz = coord[r*3+2] - coord[c*3+2];
    float rad = dx*dx + dy*dy + dz*dz;
    f32x4 cdv = {dx, dy, dz, rad};
    *(f32x4*)(cd4 + (size_t)e*4) = cdv;

    float kin[7];
    #pragma unroll
    for (int a = 0; a < 6; ++a) kin[a] = eattr[(size_t)e*6 + a];
    kin[6] = rad;

    float k1[64];
    #pragma unroll
    for (int j = 0; j < 64; j += 4) {
        f32x4 a = *(const f32x4*)(b1 + j);
        #pragma unroll
        for (int t = 0; t < 7; ++t)
            a += kin[t] * (*(const f32x4*)(w1 + t*64 + j));
        a = relu4(a);
        k1[j+0] = a.x; k1[j+1] = a.y; k1[j+2] = a.z; k1[j+3] = a.w;
    }
    // second layer: weights read at uniform addresses -> scalar loads
    for (int c2 = 0; c2 < 128; c2 += 4) {
        f32x4 a = *(const f32x4*)(b2 + c2);
        #pragma unroll
        for (int c1 = 0; c1 < 64; ++c1)
            a += k1[c1] * (*(const f32x4*)(w2 + c1*128 + c2));
        a = relu4(a);
        bf16x4 p = {(__bf16)a.x, (__bf16)a.y, (__bf16)a.z, (__bf16)a.w};
        *(bf16x4*)(kbf + (size_t)e*128 + c2) = p;
    }
}

// Fused big GEMM: m[e,i] = sum_j (k[e,:]@W3[:, i*32+j] + b3[i*32+j]) * h[col[e]][j]
// 1 wave per block, 64 edges per block. m stored transposed [32][E] (coalesced).
__global__ void k_gemm(const __bf16* __restrict__ kbf, const __bf16* __restrict__ w3sw,
                       const float* __restrict__ b3, const float* __restrict__ h,
                       const int* __restrict__ eidx, float* __restrict__ m_t) {
    __shared__ float wk[64 * 34];          // row pad 34 -> <=2-way bank conflicts
    const int lane = threadIdx.x;          // 0..63
    const int q = lane >> 4, t = lane & 15;
    const int base = blockIdx.x * 64;

    // gather h[col] for this lane's edge into registers
    int eg = base + lane;
    int egc = eg < NE ? eg : NE - 1;
    int col = eidx[NE + egc];
    float hcol[32];
    const f32x4* hp = (const f32x4*)(h + (size_t)col * 32);
    #pragma unroll
    for (int v = 0; v < 8; ++v) {
        f32x4 hv = hp[v];
        hcol[v*4+0] = hv.x; hcol[v*4+1] = hv.y; hcol[v*4+2] = hv.z; hcol[v*4+3] = hv.w;
    }

    // A fragments: lane supplies A[m=t][k=q*8..q*8+7] for 4 M-tiles x 4 K-steps
    bf16x8 afrag[4][4];
    #pragma unroll
    for (int mt = 0; mt < 4; ++mt) {
        int ea = base + mt*16 + t;
        ea = ea < NE ? ea : NE - 1;
        const __bf16* kr = kbf + (size_t)ea * 128 + q * 8;
        #pragma unroll
        for (int ks = 0; ks < 4; ++ks)
            afrag[mt][ks] = *(const bf16x8*)(kr + ks * 32);
    }

    const bool wvalid = eg < NE;
    const float* wkrow = wk + lane * 34;

    for (int i = 0; i < 32; ++i) {
        f32x4 acc[4][2];
        #pragma unroll
        for (int mt = 0; mt < 4; ++mt) {
            acc[mt][0] = (f32x4){0.f, 0.f, 0.f, 0.f};
            acc[mt][1] = (f32x4){0.f, 0.f, 0.f, 0.f};
        }
        const __bf16* wb = w3sw + (size_t)i * 4096;
        #pragma unroll
        for (int jt = 0; jt < 2; ++jt) {
            #pragma unroll
            for (int ks = 0; ks < 4; ++ks) {
                bf16x8 bfrag = *(const bf16x8*)(wb + ((jt*4 + ks)*64 + lane) * 8);
                #pragma unroll
                for (int mt = 0; mt < 4; ++mt)
                    acc[mt][jt] = __builtin_amdgcn_mfma_f32_16x16x32_bf16(
                        afrag[mt][ks], bfrag, acc[mt][jt], 0, 0, 0);
            }
        }
        float bias0 = b3[i*32 + t];
        float bias1 = b3[i*32 + 16 + t];
        __syncthreads();   // prev iteration's reads done
        #pragma unroll
        for (int mt = 0; mt < 4; ++mt) {
            #pragma unroll
            for (int r = 0; r < 4; ++r) {
                int row = mt*16 + q*4 + r;
                wk[row*34 + t]      = acc[mt][0][r] + bias0;
                wk[row*34 + 16 + t] = acc[mt][1][r] + bias1;
            }
        }
        __syncthreads();
        float s = 0.f;
        #pragma unroll
        for (int j = 0; j < 32; ++j) s += wkrow[j] * hcol[j];
        if (wvalid) m_t[(size_t)i * NE + eg] = s;
    }
}

// phi MLP + atomic scatter of coord_diff*phi and m into per-node accumulators
__global__ void k_phi(const float* __restrict__ m_t, const float* __restrict__ cd4,
                      const int* __restrict__ eidx,
                      const float* __restrict__ cm_w1, const float* __restrict__ cm_b1,
                      const float* __restrict__ cm_w2,
                      float* __restrict__ acc_coord, float* __restrict__ acc_m) {
    int e = blockIdx.x * blockDim.x + threadIdx.x;
    if (e >= NE) return;
    float mv[32];
    #pragma unroll
    for (int i = 0; i < 32; ++i) mv[i] = m_t[(size_t)i * NE + e];
    float phi = 0.f;
    for (int o = 0; o < 32; o += 4) {
        f32x4 a = *(const f32x4*)(cm_b1 + o);
        #pragma unroll
        for (int i = 0; i < 32; ++i)
            a += mv[i] * (*(const f32x4*)(cm_w1 + i*32 + o));
        a = relu4(a);
        f32x4 w2 = *(const f32x4*)(cm_w2 + o);
        phi += a.x*w2.x + a.y*w2.y + a.z*w2.z + a.w*w2.w;
    }
    int r = eidx[e];
    f32x4 cd = *(const f32x4*)(cd4 + (size_t)e*4);
    atomicAdd(&acc_coord[r*3+0], cd.x * phi);
    atomicAdd(&acc_coord[r*3+1], cd.y * phi);
    atomicAdd(&acc_coord[r*3+2], cd.z * phi);
    float* am = acc_m + (size_t)r * 32;
    #pragma unroll
    for (int i = 0; i < 32; ++i) atomicAdd(&am[i], mv[i]);
}

__global__ void k_node(const float* __restrict__ acc_coord, const float* __restrict__ acc_m,
                       const float* __restrict__ deg_inv,
                       float* __restrict__ coord, float* __restrict__ h) {
    int n = blockIdx.x * blockDim.x + threadIdx.x;
    if (n >= NN) return;
    float di = deg_inv[n];
    coord[n*3+0] += acc_coord[n*3+0] * di;
    coord[n*3+1] += acc_coord[n*3+1] * di;
    coord[n*3+2] += acc_coord[n*3+2] * di;
    #pragma unroll
    for (int j = 0; j < 32; j += 4) {
        f32x4 hv = *(const f32x4*)(h + n*32 + j);
        f32x4 av = *(const f32x4*)(acc_m + n*32 + j);
        hv = relu4(hv + av * di);
        *(f32x4*)(h + n*32 + j) = hv;
    }
}

__global__ void k_final(const float* __restrict__ h, const float* __restrict__ coord,
                        const float* __restrict__ fw1, const float* __restrict__ fb1,
                        const float* __restrict__ fw2, const float* __restrict__ fb2,
                        float* __restrict__ out) {
    int n = blockIdx.x * blockDim.x + threadIdx.x;
    if (n >= NN) return;
    float hreg[32];
    #pragma unroll
    for (int i = 0; i < 32; ++i) hreg[i] = h[n*32 + i];
    float ov = fb2[0];
    for (int o = 0; o < 64; o += 4) {
        f32x4 a = *(const f32x4*)(fb1 + o);
        #pragma unroll
        for (int i = 0; i < 32; ++i)
            a += hreg[i] * (*(const f32x4*)(fw1 + i*64 + o));
        a = relu4(a);
        f32x4 w2 = *(const f32x4*)(fw2 + o);
        ov += a.x*w2.x + a.y*w2.y + a.z*w2.z + a.w*w2.w;
    }
    out[n] = ov;                       // output 0: [N,1]
    out[NN + n*3 + 0] = coord[n*3+0];  // output 1: coord [N,3]
    out[NN + n*3 + 1] = coord[n*3+1];
    out[NN + n*3 + 2] = coord[n*3+2];
}

// ---------------- launch ----------------

extern "C" void kernel_launch(void* const* d_in, const int* in_sizes, int n_in,
                              void* d_out, int out_size, void* d_ws, size_t ws_size,
                              hipStream_t stream) {
    const float* x      = (const float*)d_in[0];
    const int*   eidx   = (const int*)  d_in[1];
    const float* eattr  = (const float*)d_in[2];
    const float* cinit  = (const float*)d_in[3];
    const float* fc1w   = (const float*)d_in[4];
    const float* fc1b   = (const float*)d_in[5];
    const float* kw1    = (const float*)d_in[6];
    const float* kb1    = (const float*)d_in[7];
    const float* kw2    = (const float*)d_in[8];
    const float* kb2    = (const float*)d_in[9];
    const float* kw3    = (const float*)d_in[10];
    const float* kb3    = (const float*)d_in[11];
    const float* cmw1   = (const float*)d_in[12];
    const float* cmb1   = (const float*)d_in[13];
    const float* cmw2   = (const float*)d_in[14];
    const float* f2w1   = (const float*)d_in[15];
    const float* f2b1   = (const float*)d_in[16];
    const float* f2w2   = (const float*)d_in[17];
    const float* f2b2   = (const float*)d_in[18];
    float* out = (float*)d_out;

    // workspace carve-up (256B aligned slots)
    char* p = (char*)d_ws;
    auto carve = [&](size_t bytes) {
        void* r = (void*)p;
        p += (bytes + 255) & ~(size_t)255;
        return r;
    };
    float*  h        = (float*) carve((size_t)NN * 32 * 4);
    float*  coord    = (float*) carve((size_t)NN * 3 * 4);
    int*    deg      = (int*)   carve((size_t)NN * 4);
    float*  deg_inv  = (float*) carve((size_t)NN * 4);
    float*  acc      = (float*) carve((size_t)NN * 35 * 4);  // [N*3 coord | N*32 m]
    float*  cd4      = (float*) carve((size_t)NE * 4 * 4);
    __bf16* kbf      = (__bf16*)carve((size_t)NE * 128 * 2);
    __bf16* w3sw     = (__bf16*)carve((size_t)131072 * 2);
    float*  m_t      = (float*) carve((size_t)32 * NE * 4);
    float*  acc_c    = acc;
    float*  acc_m    = acc + (size_t)NN * 3;

    const int TB = 256;
    dim3 gE((NE + TB - 1) / TB), gN((NN + TB - 1) / TB), b(TB);

    hipMemsetAsync(deg, 0, (size_t)NN * 4, stream);
    k_deg <<<gE, b, 0, stream>>>(eidx, deg);
    k_init<<<gN, b, 0, stream>>>(x, fc1w, fc1b, cinit, deg, h, coord, deg_inv);
    k_w3sw<<<512, b, 0, stream>>>(kw3, w3sw);

    for (int d = 0; d < 3; ++d) {
        hipMemsetAsync(acc, 0, (size_t)NN * 35 * 4, stream);
        k_edge<<<gE, b, 0, stream>>>(coord, eidx, eattr, kw1, kb1, kw2, kb2, cd4, kbf);
        k_gemm<<<dim3((NE + 63) / 64), dim3(64), 0, stream>>>(kbf, w3sw, kb3, h, eidx, m_t);
        k_phi <<<gE, b, 0, stream>>>(m_t, cd4, eidx, cmw1, cmb1, cmw2, acc_c, acc_m);
        k_node<<<gN, b, 0, stream>>>(acc_c, acc_m, deg_inv, coord, h);
    }
    k_final<<<gN, b, 0, stream>>>(h, coord, f2w1, f2b1, f2w2, f2b2, out);
}

// Round 2
// 2440.069 us; speedup vs baseline: 1.0641x; 1.0641x over previous
//
#include <hip/hip_runtime.h>
#include <hip/hip_bf16.h>

#define NN 10000
#define NE 100000

typedef __bf16 bf16x8 __attribute__((ext_vector_type(8)));
typedef __bf16 bf16x4 __attribute__((ext_vector_type(4)));
typedef float  f32x4  __attribute__((ext_vector_type(4)));

__device__ __forceinline__ f32x4 relu4(f32x4 a) {
    a.x = fmaxf(a.x, 0.f); a.y = fmaxf(a.y, 0.f);
    a.z = fmaxf(a.z, 0.f); a.w = fmaxf(a.w, 0.f);
    return a;
}

// ---------------- one-time kernels ----------------

__global__ void k_deg(const int* __restrict__ eidx, int* __restrict__ deg) {
    int e = blockIdx.x * blockDim.x + threadIdx.x;
    if (e < NE) atomicAdd(&deg[eidx[e]], 1);
}

__global__ void k_init(const float* __restrict__ x, const float* __restrict__ fc1w,
                       const float* __restrict__ fc1b, const float* __restrict__ cinit,
                       const int* __restrict__ deg,
                       float* __restrict__ h, float* __restrict__ coord,
                       float* __restrict__ deg_inv) {
    int n = blockIdx.x * blockDim.x + threadIdx.x;
    if (n >= NN) return;
    float x0 = x[n*3+0], x1 = x[n*3+1], x2 = x[n*3+2];
    #pragma unroll
    for (int j = 0; j < 32; j += 4) {
        f32x4 a = *(const f32x4*)(fc1b + j);
        a += x0 * (*(const f32x4*)(fc1w + 0*32 + j));
        a += x1 * (*(const f32x4*)(fc1w + 1*32 + j));
        a += x2 * (*(const f32x4*)(fc1w + 2*32 + j));
        *(f32x4*)(h + n*32 + j) = a;   // no relu on fc1 (matches reference)
    }
    coord[n*3+0] = cinit[n*3+0];
    coord[n*3+1] = cinit[n*3+1];
    coord[n*3+2] = cinit[n*3+2];
    int d = deg[n];
    deg_inv[n] = 1.0f / (float)(d > 1 ? d : 1);
}

// Swizzle ker_w3 [128,1024] fp32 -> bf16 in MFMA-B fragment order.
__global__ void k_w3sw(const float* __restrict__ w3, __bf16* __restrict__ w3sw) {
    int t = blockIdx.x * blockDim.x + threadIdx.x;   // 0 .. 131071
    int jj = t & 7;
    int L  = (t >> 3) & 63;
    int ks = (t >> 9) & 3;
    int jt = (t >> 11) & 1;
    int i  = t >> 12;
    int c    = ks*32 + (L >> 4)*8 + jj;              // K index 0..127
    int colv = i*32 + jt*16 + (L & 15);              // output col 0..1023
    w3sw[t] = (__bf16)w3[c*1024 + colv];
}

// ---------------- per-layer kernels ----------------

// Per-edge: coord_diff, radial, kernel MLP 7->64->128 (relu), store k as bf16 [E,128].
// __launch_bounds__(256,4): 128-VGPR budget so k1[64] stays in registers
// (at the default 64-VGPR cap it spilled -> 866 MB scratch FETCH, 523 us).
__global__ __launch_bounds__(256, 4)
void k_edge(const float* __restrict__ coord, const int* __restrict__ eidx,
            const float* __restrict__ eattr,
            const float* __restrict__ w1, const float* __restrict__ b1,
            const float* __restrict__ w2, const float* __restrict__ b2,
            float* __restrict__ cd4, __bf16* __restrict__ kbf) {
    int e = blockIdx.x * blockDim.x + threadIdx.x;
    if (e >= NE) return;
    int r = eidx[e], c = eidx[NE + e];
    float dx = coord[r*3+0] - coord[c*3+0];
    float dy = coord[r*3+1] - coord[c*3+1];
    float dz = coord[r*3+2] - coord[c*3+2];
    float rad = dx*dx + dy*dy + dz*dz;
    f32x4 cdv = {dx, dy, dz, rad};
    *(f32x4*)(cd4 + (size_t)e*4) = cdv;

    float kin[7];
    #pragma unroll
    for (int a = 0; a < 6; ++a) kin[a] = eattr[(size_t)e*6 + a];
    kin[6] = rad;

    float k1[64];
    #pragma unroll
    for (int j = 0; j < 64; j += 4) {
        f32x4 a = *(const f32x4*)(b1 + j);
        #pragma unroll
        for (int t = 0; t < 7; ++t)
            a += kin[t] * (*(const f32x4*)(w1 + t*64 + j));
        a = relu4(a);
        k1[j+0] = a.x; k1[j+1] = a.y; k1[j+2] = a.z; k1[j+3] = a.w;
    }
    // second layer: weight reads are wave-uniform -> scalar loads
    for (int c2 = 0; c2 < 128; c2 += 4) {
        f32x4 a = *(const f32x4*)(b2 + c2);
        #pragma unroll
        for (int c1 = 0; c1 < 64; ++c1)
            a += k1[c1] * (*(const f32x4*)(w2 + c1*128 + c2));
        a = relu4(a);
        bf16x4 p = {(__bf16)a.x, (__bf16)a.y, (__bf16)a.z, (__bf16)a.w};
        *(bf16x4*)(kbf + (size_t)e*128 + c2) = p;
    }
}

// Fused: big GEMM (E x 128 x 1024) with einsum epilogue -> m[e][i] in regs,
// then phi MLP + atomic scatter. One wave / 64 edges per block.
__global__ __launch_bounds__(64, 1)
void k_gemm(const __bf16* __restrict__ kbf, const __bf16* __restrict__ w3sw,
            const float* __restrict__ b3, const float* __restrict__ h,
            const int* __restrict__ eidx, const float* __restrict__ cd4,
            const float* __restrict__ cm_w1, const float* __restrict__ cm_b1,
            const float* __restrict__ cm_w2,
            float* __restrict__ acc_coord, float* __restrict__ acc_m) {
    __shared__ float wk[64 * 34];          // row pad 34 -> <=2-way bank conflicts
    const int lane = threadIdx.x;          // 0..63
    const int q = lane >> 4, t = lane & 15;
    const int base = blockIdx.x * 64;

    // gather h[col] for this lane's edge into registers
    int eg = base + lane;
    int egc = eg < NE ? eg : NE - 1;
    int col = eidx[NE + egc];
    float hcol[32];
    const f32x4* hp = (const f32x4*)(h + (size_t)col * 32);
    #pragma unroll
    for (int v = 0; v < 8; ++v) {
        f32x4 hv = hp[v];
        hcol[v*4+0] = hv.x; hcol[v*4+1] = hv.y; hcol[v*4+2] = hv.z; hcol[v*4+3] = hv.w;
    }

    // A fragments: lane supplies A[m=t][k=q*8..q*8+7] for 4 M-tiles x 4 K-steps
    bf16x8 afrag[4][4];
    #pragma unroll
    for (int mt = 0; mt < 4; ++mt) {
        int ea = base + mt*16 + t;
        ea = ea < NE ? ea : NE - 1;
        const __bf16* kr = kbf + (size_t)ea * 128 + q * 8;
        #pragma unroll
        for (int ks = 0; ks < 4; ++ks)
            afrag[mt][ks] = *(const bf16x8*)(kr + ks * 32);
    }

    const bool wvalid = eg < NE;
    const float* wkrow = wk + lane * 34;
    float mv[32];

    for (int i = 0; i < 32; ++i) {
        f32x4 acc[4][2];
        #pragma unroll
        for (int mt = 0; mt < 4; ++mt) {
            acc[mt][0] = (f32x4){0.f, 0.f, 0.f, 0.f};
            acc[mt][1] = (f32x4){0.f, 0.f, 0.f, 0.f};
        }
        const __bf16* wb = w3sw + (size_t)i * 4096;
        #pragma unroll
        for (int jt = 0; jt < 2; ++jt) {
            #pragma unroll
            for (int ks = 0; ks < 4; ++ks) {
                bf16x8 bfrag = *(const bf16x8*)(wb + ((jt*4 + ks)*64 + lane) * 8);
                #pragma unroll
                for (int mt = 0; mt < 4; ++mt)
                    acc[mt][jt] = __builtin_amdgcn_mfma_f32_16x16x32_bf16(
                        afrag[mt][ks], bfrag, acc[mt][jt], 0, 0, 0);
            }
        }
        float bias0 = b3[i*32 + t];
        float bias1 = b3[i*32 + 16 + t];
        __syncthreads();   // prev iteration's reads done
        #pragma unroll
        for (int mt = 0; mt < 4; ++mt) {
            #pragma unroll
            for (int r = 0; r < 4; ++r) {
                int row = mt*16 + q*4 + r;
                wk[row*34 + t]      = acc[mt][0][r] + bias0;
                wk[row*34 + 16 + t] = acc[mt][1][r] + bias1;
            }
        }
        __syncthreads();
        float s = 0.f;
        #pragma unroll
        for (int j = 0; j < 32; ++j) s += wkrow[j] * hcol[j];
        mv[i] = s;
    }

    // ---- fused phi MLP (32 -> 32 relu -> 1) ----
    float phi = 0.f;
    for (int o = 0; o < 32; o += 4) {
        f32x4 a = *(const f32x4*)(cm_b1 + o);
        #pragma unroll
        for (int i = 0; i < 32; ++i)
            a += mv[i] * (*(const f32x4*)(cm_w1 + i*32 + o));
        a = relu4(a);
        f32x4 w2 = *(const f32x4*)(cm_w2 + o);
        phi += a.x*w2.x + a.y*w2.y + a.z*w2.z + a.w*w2.w;
    }

    if (wvalid) {
        int r = eidx[eg];
        f32x4 cd = *(const f32x4*)(cd4 + (size_t)eg*4);
        atomicAdd(&acc_coord[r*3+0], cd.x * phi);
        atomicAdd(&acc_coord[r*3+1], cd.y * phi);
        atomicAdd(&acc_coord[r*3+2], cd.z * phi);
        float* am = acc_m + (size_t)r * 32;
        #pragma unroll
        for (int i = 0; i < 32; ++i) atomicAdd(&am[i], mv[i]);
    }
}

__global__ void k_node(const float* __restrict__ acc_coord, const float* __restrict__ acc_m,
                       const float* __restrict__ deg_inv,
                       float* __restrict__ coord, float* __restrict__ h) {
    int n = blockIdx.x * blockDim.x + threadIdx.x;
    if (n >= NN) return;
    float di = deg_inv[n];
    coord[n*3+0] += acc_coord[n*3+0] * di;
    coord[n*3+1] += acc_coord[n*3+1] * di;
    coord[n*3+2] += acc_coord[n*3+2] * di;
    #pragma unroll
    for (int j = 0; j < 32; j += 4) {
        f32x4 hv = *(const f32x4*)(h + n*32 + j);
        f32x4 av = *(const f32x4*)(acc_m + n*32 + j);
        hv = relu4(hv + av * di);
        *(f32x4*)(h + n*32 + j) = hv;
    }
}

__global__ __launch_bounds__(256, 4)
void k_final(const float* __restrict__ h, const float* __restrict__ coord,
             const float* __restrict__ fw1, const float* __restrict__ fb1,
             const float* __restrict__ fw2, const float* __restrict__ fb2,
             float* __restrict__ out) {
    int n = blockIdx.x * blockDim.x + threadIdx.x;
    if (n >= NN) return;
    float hreg[32];
    #pragma unroll
    for (int i = 0; i < 32; ++i) hreg[i] = h[n*32 + i];
    float ov = fb2[0];
    for (int o = 0; o < 64; o += 4) {
        f32x4 a = *(const f32x4*)(fb1 + o);
        #pragma unroll
        for (int i = 0; i < 32; ++i)
            a += hreg[i] * (*(const f32x4*)(fw1 + i*64 + o));
        a = relu4(a);
        f32x4 w2 = *(const f32x4*)(fw2 + o);
        ov += a.x*w2.x + a.y*w2.y + a.z*w2.z + a.w*w2.w;
    }
    out[n] = ov;                       // output 0: [N,1]
    out[NN + n*3 + 0] = coord[n*3+0];  // output 1: coord [N,3]
    out[NN + n*3 + 1] = coord[n*3+1];
    out[NN + n*3 + 2] = coord[n*3+2];
}

// ---------------- launch ----------------

extern "C" void kernel_launch(void* const* d_in, const int* in_sizes, int n_in,
                              void* d_out, int out_size, void* d_ws, size_t ws_size,
                              hipStream_t stream) {
    const float* x      = (const float*)d_in[0];
    const int*   eidx   = (const int*)  d_in[1];
    const float* eattr  = (const float*)d_in[2];
    const float* cinit  = (const float*)d_in[3];
    const float* fc1w   = (const float*)d_in[4];
    const float* fc1b   = (const float*)d_in[5];
    const float* kw1    = (const float*)d_in[6];
    const float* kb1    = (const float*)d_in[7];
    const float* kw2    = (const float*)d_in[8];
    const float* kb2    = (const float*)d_in[9];
    const float* kw3    = (const float*)d_in[10];
    const float* kb3    = (const float*)d_in[11];
    const float* cmw1   = (const float*)d_in[12];
    const float* cmb1   = (const float*)d_in[13];
    const float* cmw2   = (const float*)d_in[14];
    const float* f2w1   = (const float*)d_in[15];
    const float* f2b1   = (const float*)d_in[16];
    const float* f2w2   = (const float*)d_in[17];
    const float* f2b2   = (const float*)d_in[18];
    float* out = (float*)d_out;

    // workspace carve-up (256B aligned slots)
    char* p = (char*)d_ws;
    auto carve = [&](size_t bytes) {
        void* r = (void*)p;
        p += (bytes + 255) & ~(size_t)255;
        return r;
    };
    float*  h        = (float*) carve((size_t)NN * 32 * 4);
    float*  coord    = (float*) carve((size_t)NN * 3 * 4);
    int*    deg      = (int*)   carve((size_t)NN * 4);
    float*  deg_inv  = (float*) carve((size_t)NN * 4);
    float*  acc      = (float*) carve((size_t)NN * 35 * 4);  // [N*3 coord | N*32 m]
    float*  cd4      = (float*) carve((size_t)NE * 4 * 4);
    __bf16* kbf      = (__bf16*)carve((size_t)NE * 128 * 2);
    __bf16* w3sw     = (__bf16*)carve((size_t)131072 * 2);
    float*  acc_c    = acc;
    float*  acc_m    = acc + (size_t)NN * 3;

    const int TB = 256;
    dim3 gE((NE + TB - 1) / TB), gN((NN + TB - 1) / TB), b(TB);

    hipMemsetAsync(deg, 0, (size_t)NN * 4, stream);
    k_deg <<<gE, b, 0, stream>>>(eidx, deg);
    k_init<<<gN, b, 0, stream>>>(x, fc1w, fc1b, cinit, deg, h, coord, deg_inv);
    k_w3sw<<<512, b, 0, stream>>>(kw3, w3sw);

    for (int d = 0; d < 3; ++d) {
        hipMemsetAsync(acc, 0, (size_t)NN * 35 * 4, stream);
        k_edge<<<gE, b, 0, stream>>>(coord, eidx, eattr, kw1, kb1, kw2, kb2, cd4, kbf);
        k_gemm<<<dim3((NE + 63) / 64), dim3(64), 0, stream>>>(
            kbf, w3sw, kb3, h, eidx, cd4, cmw1, cmb1, cmw2, acc_c, acc_m);
        k_node<<<gN, b, 0, stream>>>(acc_c, acc_m, deg_inv, coord, h);
    }
    k_final<<<gN, b, 0, stream>>>(h, coord, f2w1, f2b1, f2w2, f2b2, out);
}